// Round 24
// baseline (334.741 us; speedup 1.0000x reference)
//
#include <hip/hip_runtime.h>
#include <hip/hip_bf16.h>
#include <math.h>

// Problem constants
#define BB 4
#define TT 1536
#define CC 1536
#define HH 8
#define KK 64
#define VV 192
#define FF 192
#define EE 1536   // H*V
#define HK 512    // H*K
#define P2 3071   // 2T-1
#define RKROWS 3072  // P2 + 1 pad row (read by MFMA band, scatter-masked)
#define NQKV 2560    // HK + HK + EE (merged qkv weight rows)

typedef __attribute__((ext_vector_type(8))) __bf16 bf16x8;
typedef __attribute__((ext_vector_type(4))) float f32x4;
typedef __attribute__((ext_vector_type(4))) unsigned short us4;
typedef __attribute__((ext_vector_type(8))) unsigned short us8;

__device__ __forceinline__ unsigned short f2bf(float f) {
  union { float f; unsigned int u; } x; x.f = f;
  unsigned int r = x.u + 0x7fffu + ((x.u >> 16) & 1u);
  return (unsigned short)(r >> 16);
}

__device__ __forceinline__ void gload_lds16(const unsigned short* g, unsigned short* l) {
  __builtin_amdgcn_global_load_lds((const __attribute__((address_space(1))) unsigned int*)g,
                                   (__attribute__((address_space(3))) unsigned int*)l, 16, 0, 0);
}

// ---------------------------------------------------------------------------
// Fused: all six f32->bf16 conversions + pos_raw basis computation, one grid.
// cvt blocks [0, CVT_BLKS); pos blocks [CVT_BLKS, CVT_BLKS + POS_BLKS).
// ---------------------------------------------------------------------------
#define N4_X  (BB * TT * CC / 4)   // 2359296
#define N4_W  (HK * CC / 4)        // 196608
#define N4_V  (EE * CC / 4)        // 589824
#define N4_E  (EE * EE / 4)        // 589824
#define N4_R  (HK * FF / 4)        // 24576
#define N4_TOT (N4_X + 2 * N4_W + N4_V + N4_E + N4_R)  // 3956736
#define CVT_BLKS ((N4_TOT + 255) / 256)
#define POS_BLKS ((P2 + 255) / 256)

__global__ void cvt_pos_fused(const float* __restrict__ x, const float* __restrict__ Wq,
                              const float* __restrict__ Wk, const float* __restrict__ Wv,
                              const float* __restrict__ We, const float* __restrict__ Wrk,
                              unsigned short* __restrict__ xb, unsigned short* __restrict__ Wqkvb,
                              unsigned short* __restrict__ Web, unsigned short* __restrict__ Wrkb,
                              float* __restrict__ pe_half, unsigned int* __restrict__ gmax) {
  if ((int)blockIdx.x < CVT_BLKS) {
    int i = blockIdx.x * blockDim.x + threadIdx.x;
    if (i >= N4_TOT) return;
    const float* src;
    unsigned short* dst;
    int off;
    if (i < N4_X) {
      src = x; dst = xb; off = i;
    } else if (i < N4_X + N4_W) {
      src = Wq; dst = Wqkvb; off = i - N4_X;
    } else if (i < N4_X + 2 * N4_W) {
      src = Wk; dst = Wqkvb + (size_t)HK * CC; off = i - N4_X - N4_W;
    } else if (i < N4_X + 2 * N4_W + N4_V) {
      src = Wv; dst = Wqkvb + (size_t)2 * HK * CC; off = i - N4_X - 2 * N4_W;
    } else if (i < N4_X + 2 * N4_W + N4_V + N4_E) {
      src = We; dst = Web; off = i - N4_X - 2 * N4_W - N4_V;
    } else {
      src = Wrk; dst = Wrkb; off = i - N4_X - 2 * N4_W - N4_V - N4_E;
    }
    float4 v = *(const float4*)(src + (size_t)off * 4);
    us4 w;
    w[0] = f2bf(v.x); w[1] = f2bf(v.y); w[2] = f2bf(v.z); w[3] = f2bf(v.w);
    *(us4*)(dst + (size_t)off * 4) = w;
    return;
  }

  // ---- pos_raw part (validated r1 body) ----
  int m = ((int)blockIdx.x - CVT_BLKS) * blockDim.x + threadIdx.x;
  if (m >= P2) return;
  float p = (float)(m - (TT - 1));
  float ap = fabsf(p);
  const int fs = FF / 6;  // 32
  float* row = pe_half + (size_t)m * (FF / 2);

  const double lo = 3.0, hi = log2((double)TT);
  for (int i = 0; i < fs; ++i) {
    double hl = exp2(lo + (hi - lo) * (double)i / (double)(fs - 1));
    row[i] = exp2f((float)(-(double)ap / hl));
  }
  for (int i = 0; i < fs; ++i) {
    float w = exp2f((float)(i + 1)) - 1.0f;
    row[fs + i] = (w > ap) ? 1.0f : 0.0f;
  }
  float lmax = 0.0f;
  const float stddev = (float)TT / (2.0f * (float)fs);
  for (int i = 0; i < fs; ++i) {
    float mean = (float)((double)TT / fs + ((double)TT - (double)TT / fs) * (double)i / (double)(fs - 1));
    float conc = (mean / stddev) * (mean / stddev);
    float rate = mean / (stddev * stddev);
    float logp;
    if (ap > 0.0f)
      logp = (conc - 1.0f) * logf(ap) - rate * ap - (lgammaf(conc) - conc * logf(rate));
    else
      logp = -INFINITY;
    float prob = expf(logp) + 1e-8f;
    row[2 * fs + i] = prob;
    lmax = fmaxf(lmax, prob);
  }
  atomicMax(gmax, __float_as_uint(lmax));
}

// pass 2: normalize gamma, assemble full pe (bf16) with sign copy
__global__ void pos_assemble_kernel(const float* __restrict__ pe_half,
                                    const unsigned int* __restrict__ gmax,
                                    unsigned short* __restrict__ pe_b) {
  int idx = blockIdx.x * blockDim.x + threadIdx.x;
  if (idx >= P2 * (FF / 2)) return;
  int m = idx / (FF / 2);
  int f = idx % (FF / 2);
  float val = pe_half[idx];
  if (f >= 2 * (FF / 6)) val = val / __uint_as_float(*gmax);
  float p = (float)(m - (TT - 1));
  float sign = (p > 0.0f) ? 1.0f : ((p < 0.0f) ? -1.0f : 0.0f);
  pe_b[(size_t)m * FF + f] = f2bf(val);
  pe_b[(size_t)m * FF + (FF / 2) + f] = f2bf(sign * val);
}

// ---------------------------------------------------------------------------
// bf16 MFMA GEMM body (r22/r23-validated). 128x128 tile, BK=32, 4 waves,
// XCD-chunked swizzle. RSTG=true: reg-staged + LDS dbuf, 1 barrier/K-step.
// RSTG=false: global_load_lds, 2 barriers/K-step.
// MODE 1: f32 out + bias. MODE 4: Rkh. MODE 6: merged qkv epilogue.
// ---------------------------------------------------------------------------
template <int MODE, bool RSTG>
__device__ __forceinline__ void bgemm_body(unsigned short* As, unsigned short* Bs,
                                           int bid, int nwg,
                                           const unsigned short* __restrict__ A,
                                           const unsigned short* __restrict__ Bw,
                                           const float* __restrict__ bias,
                                           const float* __restrict__ bias2,
                                           float* __restrict__ Cc,
                                           unsigned short* __restrict__ O1,
                                           unsigned short* __restrict__ O2,
                                           unsigned short* __restrict__ O3,
                                           unsigned short* __restrict__ O4,
                                           int M, int N, int Kd) {
  const int tid = threadIdx.x;
  const int lane = tid & 63;
  const int wave = tid >> 6;
  const int fr = lane & 15, fq = lane >> 4;
  const int wrow = (wave >> 1) * 64, wcol = (wave & 1) * 64;

  // XCD-chunked swizzle (bijective; nwg % 8 == 0)
  const int nbx = N >> 7;
  const int swz = (bid & 7) * (nwg >> 3) + (bid >> 3);
  const int row0 = (swz / nbx) * 128, col0 = (swz % nbx) * 128;

  const int r_c0 = tid >> 2, s_c0 = tid & 3;
  const int r_c1 = (tid + 256) >> 2, s_c1 = tid & 3;
  const int sw_c0 = s_c0 ^ ((r_c0 >> 1) & 3);
  const int sw_c1 = s_c1 ^ ((r_c1 >> 1) & 3);
  const unsigned short* Asrc0 = A + (size_t)(row0 + r_c0) * Kd + sw_c0 * 8;
  const unsigned short* Asrc1 = A + (size_t)(row0 + r_c1) * Kd + sw_c1 * 8;
  const unsigned short* Bsrc0 = Bw + (size_t)(col0 + r_c0) * Kd + sw_c0 * 8;
  const unsigned short* Bsrc1 = Bw + (size_t)(col0 + r_c1) * Kd + sw_c1 * 8;

  int aoff[4], boff[4];
#pragma unroll
  for (int m = 0; m < 4; ++m) {
    int rl = wrow + m * 16 + fr;
    aoff[m] = rl * 32 + (fq ^ ((rl >> 1) & 3)) * 8;
    int cl = wcol + m * 16 + fr;
    boff[m] = cl * 32 + (fq ^ ((cl >> 1) & 3)) * 8;
  }

  f32x4 acc[4][4];
#pragma unroll
  for (int m = 0; m < 4; ++m)
#pragma unroll
    for (int n = 0; n < 4; ++n) acc[m][n] = (f32x4){0.f, 0.f, 0.f, 0.f};

  if (RSTG) {
    // ---- reg-staged + LDS dbuf: one barrier per K-step ----
    us8 rA0 = *(const us8*)(Asrc0);
    us8 rA1 = *(const us8*)(Asrc1);
    us8 rB0 = *(const us8*)(Bsrc0);
    us8 rB1 = *(const us8*)(Bsrc1);
    *(us8*)(As + (size_t)tid * 8) = rA0;
    *(us8*)(As + (size_t)(tid + 256) * 8) = rA1;
    *(us8*)(Bs + (size_t)tid * 8) = rB0;
    *(us8*)(Bs + (size_t)(tid + 256) * 8) = rB1;
    __syncthreads();  // buf0 published

    int cur = 0;
    for (int kt = 0; kt < Kd; kt += 32) {
      const bool nx = (kt + 32 < Kd);
      if (nx) {
        rA0 = *(const us8*)(Asrc0 + kt + 32);
        rA1 = *(const us8*)(Asrc1 + kt + 32);
        rB0 = *(const us8*)(Bsrc0 + kt + 32);
        rB1 = *(const us8*)(Bsrc1 + kt + 32);
      }

      const unsigned short* Ab = As + cur * (128 * 32);
      const unsigned short* Bb = Bs + cur * (128 * 32);
      bf16x8 af[4], bfr[4];
#pragma unroll
      for (int m = 0; m < 4; ++m) af[m] = *(const bf16x8*)(Ab + aoff[m]);
#pragma unroll
      for (int n = 0; n < 4; ++n) bfr[n] = *(const bf16x8*)(Bb + boff[n]);
      __builtin_amdgcn_s_setprio(1);
#pragma unroll
      for (int m = 0; m < 4; ++m)
#pragma unroll
        for (int n = 0; n < 4; ++n)
          acc[m][n] = __builtin_amdgcn_mfma_f32_16x16x32_bf16(af[m], bfr[n], acc[m][n], 0, 0, 0);
      __builtin_amdgcn_s_setprio(0);

      if (nx) {
        const int nb = cur ^ 1;
        *(us8*)(As + nb * (128 * 32) + (size_t)tid * 8) = rA0;
        *(us8*)(As + nb * (128 * 32) + (size_t)(tid + 256) * 8) = rA1;
        *(us8*)(Bs + nb * (128 * 32) + (size_t)tid * 8) = rB0;
        *(us8*)(Bs + nb * (128 * 32) + (size_t)(tid + 256) * 8) = rB1;
      }
      __syncthreads();  // seals this iter's reads + publishes buf nb
      cur ^= 1;
    }
  } else {
    // ---- global_load_lds path ----
    unsigned short* Adst0 = As + (size_t)tid * 8;
    unsigned short* Adst1 = As + (size_t)(tid + 256) * 8;
    unsigned short* Bdst0 = Bs + (size_t)tid * 8;
    unsigned short* Bdst1 = Bs + (size_t)(tid + 256) * 8;
    for (int kt = 0; kt < Kd; kt += 32) {
      gload_lds16(Asrc0 + kt, Adst0);
      gload_lds16(Asrc1 + kt, Adst1);
      gload_lds16(Bsrc0 + kt, Bdst0);
      gload_lds16(Bsrc1 + kt, Bdst1);
      __syncthreads();

      bf16x8 af[4], bfr[4];
#pragma unroll
      for (int m = 0; m < 4; ++m) af[m] = *(const bf16x8*)(As + aoff[m]);
#pragma unroll
      for (int n = 0; n < 4; ++n) bfr[n] = *(const bf16x8*)(Bs + boff[n]);
#pragma unroll
      for (int m = 0; m < 4; ++m)
#pragma unroll
        for (int n = 0; n < 4; ++n)
          acc[m][n] = __builtin_amdgcn_mfma_f32_16x16x32_bf16(af[m], bfr[n], acc[m][n], 0, 0, 0);
      __syncthreads();
    }
  }

#pragma unroll
  for (int m = 0; m < 4; ++m) {
    int Rbase = row0 + wrow + m * 16 + fq * 4;
#pragma unroll
    for (int n = 0; n < 4; ++n) {
      int Cg = col0 + wcol + n * 16 + fr;
      if (MODE == 1) {
        float bv = bias[Cg];
#pragma unroll
        for (int r = 0; r < 4; ++r)
          Cc[(size_t)(Rbase + r) * N + Cg] = acc[m][n][r] + bv;
      } else if (MODE == 4) {
        int h = Cg >> 6, k0 = Cg & 63;
#pragma unroll
        for (int r = 0; r < 4; ++r)
          O1[(((size_t)h * RKROWS + (Rbase + r)) * KK + k0)] = f2bf(acc[m][n][r]);
      } else if (MODE == 6) {
        if (Cg < HK) {
          int h = Cg >> 6, k0 = Cg & 63;
          float bw = bias[Cg], br = bias2[Cg];
#pragma unroll
          for (int r = 0; r < 4; ++r) {
            int R = Rbase + r;
            int b = R / TT, t = R - b * TT;
            size_t di = ((((size_t)b * HH + h) * TT + t) * KK + k0);
            float qv = acc[m][n][r] * 0.125f;
            O1[di] = f2bf(qv + bw);
            O2[di] = f2bf(qv + br);
          }
        } else if (Cg < 2 * HK) {
          int c = Cg - HK;
          int h = c >> 6, k0 = c & 63;
#pragma unroll
          for (int r = 0; r < 4; ++r) {
            int R = Rbase + r;
            int b = R / TT, t = R - b * TT;
            O3[((((size_t)b * HH + h) * TT + t) * KK + k0)] = f2bf(acc[m][n][r]);
          }
        } else {
          int c = Cg - 2 * HK;
          int h = c / VV, v0 = c - h * VV;
#pragma unroll
          for (int r = 0; r < 4; ++r) {
            int R = Rbase + r;
            int b = R / TT, t = R - b * TT;
            O4[((((size_t)b * HH + h) * VV + v0) * TT + t)] = f2bf(acc[m][n][r]);
          }
        }
      }
    }
  }
}

// Fused qkv (960 blocks, mode-6 dbuf) + rk (96 blocks, mode-4 gload).
#define QKV_NWG ((NQKV / 128) * ((BB * TT) / 128))   // 960
#define RK_NWG  ((HK / 128) * (RKROWS / 128))        // 96

__global__ __launch_bounds__(256) void bgemm_qkvrk(const unsigned short* __restrict__ xb,
                                                   const unsigned short* __restrict__ Wqkvb,
                                                   const float* __restrict__ rwb,
                                                   const float* __restrict__ rrb,
                                                   unsigned short* __restrict__ Qwh,
                                                   unsigned short* __restrict__ Qrh,
                                                   unsigned short* __restrict__ Kh,
                                                   unsigned short* __restrict__ Vt,
                                                   const unsigned short* __restrict__ pe_b,
                                                   const unsigned short* __restrict__ Wrkb,
                                                   unsigned short* __restrict__ Rkh) {
  __shared__ __align__(16) unsigned short As[2 * 128 * 32];
  __shared__ __align__(16) unsigned short Bs[2 * 128 * 32];
  if ((int)blockIdx.x < QKV_NWG) {
    bgemm_body<6, true>(As, Bs, blockIdx.x, QKV_NWG, xb, Wqkvb, rwb, rrb,
                        nullptr, Qwh, Qrh, Kh, Vt, BB * TT, NQKV, CC);
  } else {
    bgemm_body<4, false>(As, Bs, blockIdx.x - QKV_NWG, RK_NWG, pe_b, Wrkb, nullptr, nullptr,
                         nullptr, Rkh, nullptr, nullptr, nullptr, RKROWS, HK, FF);
  }
}

// Final projection (mode-1), now on the dbuf reg-staged path (r22 transform).
__global__ __launch_bounds__(256) void bgemm_out(const unsigned short* __restrict__ ab_b,
                                                 const unsigned short* __restrict__ Web,
                                                 const float* __restrict__ be,
                                                 float* __restrict__ out) {
  __shared__ __align__(16) unsigned short As[2 * 128 * 32];
  __shared__ __align__(16) unsigned short Bs[2 * 128 * 32];
  bgemm_body<1, true>(As, Bs, blockIdx.x, gridDim.x, ab_b, Web, be, nullptr,
                      out, nullptr, nullptr, nullptr, nullptr, BB * TT, EE, EE);
}

// ---------------------------------------------------------------------------
// Kernel A: S-GEN with REG-STAGED K/R (r18-validated). Padded LDS rows (72
// shorts). Grid: 1536 = (q-block, panel, kv-half), XCD-chunk-swizzled.
// ---------------------------------------------------------------------------
__global__ __launch_bounds__(256) void attn_sgen(const unsigned short* __restrict__ Qwh,
                                                 const unsigned short* __restrict__ Qrh,
                                                 const unsigned short* __restrict__ Kh,
                                                 const unsigned short* __restrict__ Rkh,
                                                 unsigned short* __restrict__ S,
                                                 float* __restrict__ s2) {
  const int bid = blockIdx.x;
  const int Lid = (bid & 7) * 192 + (bid >> 3);
  const int kvh = Lid & 1;
  const int q0 = ((Lid >> 1) % 24) * 64;
  const int panel = Lid / 48;               // = b*8 + h
  const int h = panel & 7;

  const int tid = threadIdx.x;
  const int wave = tid >> 6, lane = tid & 63;
  const int fr = lane & 15, fq = lane >> 4;
  const int kof = fq * 8;
  const int qs = q0 + wave * 16;
  const int qlb = fq * 4;

  __shared__ __align__(16) unsigned short Ks[64 * 72];    //  9216 B (+8 pad rows)
  __shared__ __align__(16) unsigned short Rs[128 * 72];   // 18432 B
  __shared__ __align__(16) float Lsm[4][16][68];          // 17408 B
  float(*Lw)[68] = Lsm[wave];

  const unsigned short* Qwp = Qwh + (size_t)panel * TT * KK;
  const unsigned short* Qrp = Qrh + (size_t)panel * TT * KK;
  const unsigned short* Kp  = Kh  + (size_t)panel * TT * KK;
  const unsigned short* Rp  = Rkh + (size_t)h * RKROWS * KK;
  unsigned short* Sp = S + (size_t)panel * TT * TT;

  // staging geometry: chunk row = tid>>3 (+32 per extra chunk), slot = (tid&7)*8
  const int crow = tid >> 3;        // 0..31
  const int csl  = (tid & 7) * 8;   // short offset within row

  bf16x8 aw[2], arr[2];
  {
    const unsigned short* qw = Qwp + (size_t)(qs + fr) * KK;
    const unsigned short* qr = Qrp + (size_t)(qs + fr) * KK;
    aw[0]  = *(const bf16x8*)(qw + kof);
    aw[1]  = *(const bf16x8*)(qw + 32 + kof);
    arr[0] = *(const bf16x8*)(qr + kof);
    arr[1] = *(const bf16x8*)(qr + 32 + kof);
  }

  float s_run[4] = {0.f, 0.f, 0.f, 0.f};
  const int srow = lane >> 2;        // repack: lane's source row
  const int scg = (lane & 3) * 16;   // repack: lane's col group

  // prologue: load tile 0 into regs, write to LDS (visible after 1st barrier)
  {
    const int j0 = kvh * 64;
    const unsigned short* kb = Kp + (size_t)(j0 + crow) * KK + csl;
    us8 k0 = *(const us8*)(kb);
    us8 k1 = *(const us8*)(kb + 32 * KK);
    const unsigned short* rb = Rp + (size_t)(1472 + j0 - q0 + crow) * KK + csl;
    us8 r0 = *(const us8*)(rb);
    us8 r1 = *(const us8*)(rb + 32 * KK);
    us8 r2 = *(const us8*)(rb + 64 * KK);
    us8 r3 = *(const us8*)(rb + 96 * KK);
    unsigned short* kd = Ks + (size_t)crow * 72 + csl;
    *(us8*)(kd) = k0;
    *(us8*)(kd + 32 * 72) = k1;
    unsigned short* rd = Rs + (size_t)crow * 72 + csl;
    *(us8*)(rd) = r0;
    *(us8*)(rd + 32 * 72) = r1;
    *(us8*)(rd + 64 * 72) = r2;
    *(us8*)(rd + 96 * 72) = r3;
  }

  for (int t = 0; t < 12; ++t) {
    const int j0 = kvh * 64 + t * 128;
    __syncthreads();  // tile t's ds_writes visible to all waves

    // ---- issue next tile's global loads EARLY (drain under compute) ----
    us8 nK0, nK1, nR0, nR1, nR2, nR3;
    if (t + 1 < 12) {
      const int jn = j0 + 128;
      const unsigned short* kb = Kp + (size_t)(jn + crow) * KK + csl;
      nK0 = *(const us8*)(kb);
      nK1 = *(const us8*)(kb + 32 * KK);
      const unsigned short* rb = Rp + (size_t)(1472 + jn - q0 + crow) * KK + csl;
      nR0 = *(const us8*)(rb);
      nR1 = *(const us8*)(rb + 32 * KK);
      nR2 = *(const us8*)(rb + 64 * KK);
      nR3 = *(const us8*)(rb + 96 * KK);
    }

    // ---- band logits from Rs: rows (48-16*wave) + tjb*16 + fr ----
    __builtin_amdgcn_s_setprio(1);
    f32x4 gfr[5];
#pragma unroll
    for (int tjb = 0; tjb < 5; ++tjb) {
      f32x4 acc = (f32x4){0.f, 0.f, 0.f, 0.f};
      bf16x8 bv0 = *(const bf16x8*)(Rs + (size_t)(48 - 16 * wave + tjb * 16 + fr) * 72 + kof);
      acc = __builtin_amdgcn_mfma_f32_16x16x32_bf16(arr[0], bv0, acc, 0, 0, 0);
      bf16x8 bv1 = *(const bf16x8*)(Rs + (size_t)(48 - 16 * wave + tjb * 16 + fr) * 72 + 32 + kof);
      acc = __builtin_amdgcn_mfma_f32_16x16x32_bf16(arr[1], bv1, acc, 0, 0, 0);
      gfr[tjb] = acc;
    }
    __builtin_amdgcn_s_setprio(0);
    // scatter-shift: L[q][j], j = band + q - 15 (masked; covers [0,64) fully)
#pragma unroll
    for (int tjb = 0; tjb < 5; ++tjb)
#pragma unroll
      for (int rr = 0; rr < 4; ++rr) {
        int j = tjb * 16 + fr + qlb + rr - 15;
        if (j >= 0 && j < 64) Lw[qlb + rr][j] = gfr[tjb][rr];
      }

    // ---- content logits from Ks ----
    __builtin_amdgcn_s_setprio(1);
    f32x4 cfr[4];
#pragma unroll
    for (int tj = 0; tj < 4; ++tj) {
      f32x4 acc = (f32x4){0.f, 0.f, 0.f, 0.f};
      bf16x8 bv0 = *(const bf16x8*)(Ks + (size_t)(tj * 16 + fr) * 72 + kof);
      acc = __builtin_amdgcn_mfma_f32_16x16x32_bf16(aw[0], bv0, acc, 0, 0, 0);
      bf16x8 bv1 = *(const bf16x8*)(Ks + (size_t)(tj * 16 + fr) * 72 + 32 + kof);
      acc = __builtin_amdgcn_mfma_f32_16x16x32_bf16(aw[1], bv1, acc, 0, 0, 0);
      cfr[tj] = acc;
    }
    __builtin_amdgcn_s_setprio(0);

    // ---- streaming exp: p = exp(content + rel - 20) -> Lw; s += p ----
#pragma unroll
    for (int tj = 0; tj < 4; ++tj)
#pragma unroll
      for (int rr = 0; rr < 4; ++rr) {
        float p = __expf(cfr[tj][rr] + Lw[qlb + rr][tj * 16 + fr] - 20.0f);
        Lw[qlb + rr][tj * 16 + fr] = p;
        s_run[rr] += p;
      }

    // ---- repack + coalesced bf16 store (wave-local LDS roundtrip) ----
    {
      f32x4 v0 = *(const f32x4*)&Lw[srow][scg + 0];
      f32x4 v1 = *(const f32x4*)&Lw[srow][scg + 4];
      f32x4 v2 = *(const f32x4*)&Lw[srow][scg + 8];
      f32x4 v3 = *(const f32x4*)&Lw[srow][scg + 12];
      us8 w0, w1;
#pragma unroll
      for (int i = 0; i < 4; ++i) {
        w0[i] = f2bf(v0[i]); w0[4 + i] = f2bf(v1[i]);
        w1[i] = f2bf(v2[i]); w1[4 + i] = f2bf(v3[i]);
      }
      unsigned short* dst = Sp + (size_t)(qs + srow) * TT + j0 + scg;
      *(us8*)(dst) = w0;
      *(us8*)(dst + 8) = w1;
    }

    __syncthreads();  // all waves done reading Ks/Rs for tile t

    // ---- write next tile's staged regs to LDS ----
    if (t + 1 < 12) {
      unsigned short* kd = Ks + (size_t)crow * 72 + csl;
      *(us8*)(kd) = nK0;
      *(us8*)(kd + 32 * 72) = nK1;
      unsigned short* rd = Rs + (size_t)crow * 72 + csl;
      *(us8*)(rd) = nR0;
      *(us8*)(rd + 32 * 72) = nR1;
      *(us8*)(rd + 64 * 72) = nR2;
      *(us8*)(rd + 96 * 72) = nR3;
    }
  }

  // ---- s partials: reduce over 16 fr lanes, write per-half slot ----
#pragma unroll
  for (int rr = 0; rr < 4; ++rr) {
    float s = s_run[rr];
    s += __shfl_xor(s, 1);
    s += __shfl_xor(s, 2);
    s += __shfl_xor(s, 4);
    s += __shfl_xor(s, 8);
    if (fr == 0)
      s2[((size_t)kvh * 32 + panel) * TT + qs + qlb + rr] = s;
  }
}

// ---------------------------------------------------------------------------
// Kernel B: PV GEMM, full-width 64x192 tile (r16, validated). S read once;
// Vt panel served from L2 (panel's 24 row-blocks on one XCD via swizzle).
// ---------------------------------------------------------------------------
__global__ __launch_bounds__(128) void attn_pv(const unsigned short* __restrict__ S,
                                               const unsigned short* __restrict__ Vt,
                                               const float* __restrict__ s2,
                                               unsigned short* __restrict__ ab) {
  __shared__ __align__(16) unsigned short As[64 * 32];    // 4 KB
  __shared__ __align__(16) unsigned short Bs[192 * 32];   // 12 KB
  const int bid = blockIdx.x;
  const int Lid = (bid & 7) * 96 + (bid >> 3);   // XCD-chunk swizzle
  const int rowblk = Lid % 24;
  const int panel = Lid / 24;              // = b*8 + h
  const int b = panel >> 3, h = panel & 7;
  const int row0 = rowblk * 64;

  const int tid = threadIdx.x;
  const int lane = tid & 63;
  const int wave = tid >> 6;  // 0..1
  const int fr = lane & 15, fq = lane >> 4;

  const unsigned short* Ap = S + (size_t)panel * TT * TT + (size_t)row0 * TT;
  const unsigned short* Bp = Vt + (size_t)panel * VV * TT;

  int offA[2]; unsigned short* dA[2];
#pragma unroll
  for (int c = 0; c < 2; ++c) {
    int cid = tid + 128 * c, r = cid >> 2, s = cid & 3;
    offA[c] = r * TT + ((s ^ ((r >> 1) & 3)) * 8);
    dA[c] = As + (size_t)cid * 8;
  }
  int offB[6]; unsigned short* dB[6];
#pragma unroll
  for (int c = 0; c < 6; ++c) {
    int cid = tid + 128 * c, r = cid >> 2, s = cid & 3;
    offB[c] = r * TT + ((s ^ ((r >> 1) & 3)) * 8);
    dB[c] = Bs + (size_t)cid * 8;
  }

  int aoff[4], boff[6];
#pragma unroll
  for (int m = 0; m < 4; ++m) {
    int rl = m * 16 + fr;
    aoff[m] = rl * 32 + (fq ^ ((rl >> 1) & 3)) * 8;
  }
#pragma unroll
  for (int n = 0; n < 6; ++n) {
    int cl = wave * 96 + n * 16 + fr;
    boff[n] = cl * 32 + (fq ^ ((cl >> 1) & 3)) * 8;
  }

  f32x4 acc[4][6];
#pragma unroll
  for (int m = 0; m < 4; ++m)
#pragma unroll
    for (int n = 0; n < 6; ++n) acc[m][n] = (f32x4){0.f, 0.f, 0.f, 0.f};

  for (int kt = 0; kt < TT; kt += 32) {
#pragma unroll
    for (int c = 0; c < 2; ++c) gload_lds16(Ap + offA[c] + kt, dA[c]);
#pragma unroll
    for (int c = 0; c < 6; ++c) gload_lds16(Bp + offB[c] + kt, dB[c]);
    __syncthreads();

    bf16x8 af[4], bfv[6];
#pragma unroll
    for (int m = 0; m < 4; ++m) af[m] = *(const bf16x8*)(As + aoff[m]);
#pragma unroll
    for (int n = 0; n < 6; ++n) bfv[n] = *(const bf16x8*)(Bs + boff[n]);
    __builtin_amdgcn_s_setprio(1);
#pragma unroll
    for (int m = 0; m < 4; ++m)
#pragma unroll
      for (int n = 0; n < 6; ++n)
        acc[m][n] = __builtin_amdgcn_mfma_f32_16x16x32_bf16(af[m], bfv[n], acc[m][n], 0, 0, 0);
    __builtin_amdgcn_s_setprio(0);
    __syncthreads();
  }

  const float* sA = s2 + (size_t)panel * TT;
  const float* sB = s2 + (size_t)(32 + panel) * TT;
#pragma unroll
  for (int m = 0; m < 4; ++m) {
    int Rbase = row0 + m * 16 + fq * 4;
    float invr[4];
#pragma unroll
    for (int r = 0; r < 4; ++r) invr[r] = 1.0f / (sA[Rbase + r] + sB[Rbase + r]);
#pragma unroll
    for (int n = 0; n < 6; ++n) {
      int v = wave * 96 + n * 16 + fr;
#pragma unroll
      for (int r = 0; r < 4; ++r)
        ab[((size_t)(b * TT + Rbase + r)) * EE + h * VV + v] = f2bf(acc[m][n][r] * invr[r]);
    }
  }
}

// ---------------------------------------------------------------------------
extern "C" void kernel_launch(void* const* d_in, const int* in_sizes, int n_in,
                              void* d_out, int out_size, void* d_ws, size_t ws_size,
                              hipStream_t stream) {
  const float* x   = (const float*)d_in[0];
  const float* Wq  = (const float*)d_in[1];
  const float* Wk  = (const float*)d_in[2];
  const float* Wv  = (const float*)d_in[3];
  const float* Wrk = (const float*)d_in[4];
  const float* rwb = (const float*)d_in[5];
  const float* rrb = (const float*)d_in[6];
  const float* We  = (const float*)d_in[7];
  const float* be  = (const float*)d_in[8];
  float* out = (float*)d_out;

  size_t off = 0;
  auto alloc = [&](size_t bytes) -> void* {
    void* p = (char*)d_ws + off;
    off += (bytes + 255) & ~(size_t)255;
    return p;
  };
  unsigned int* gmax = (unsigned int*)alloc(sizeof(unsigned int));
  float* pe_half = (float*)alloc((size_t)P2 * (FF / 2) * 4);
  unsigned short* pe_b   = (unsigned short*)alloc((size_t)RKROWS * FF * 2);  // row 3071 = pad
  unsigned short* xb     = (unsigned short*)alloc((size_t)BB * TT * CC * 2);
  unsigned short* Wqkvb  = (unsigned short*)alloc((size_t)NQKV * CC * 2);
  unsigned short* Web    = (unsigned short*)alloc((size_t)EE * EE * 2);
  unsigned short* Wrkb   = (unsigned short*)alloc((size_t)HK * FF * 2);
  unsigned short* Qwh    = (unsigned short*)alloc((size_t)BB * HH * TT * KK * 2);
  unsigned short* Qrh    = (unsigned short*)alloc((size_t)BB * HH * TT * KK * 2);
  unsigned short* Kh     = (unsigned short*)alloc((size_t)BB * HH * TT * KK * 2);
  unsigned short* Rkh    = (unsigned short*)alloc((size_t)HH * RKROWS * KK * 2);
  unsigned short* Vt     = (unsigned short*)alloc((size_t)BB * HH * VV * TT * 2);
  unsigned short* ab_b   = (unsigned short*)alloc((size_t)BB * TT * EE * 2);
  unsigned short* Sp     = (unsigned short*)alloc((size_t)BB * HH * TT * TT * 2);  // 151 MB
  float* s2              = (float*)alloc((size_t)2 * 32 * TT * 4);

  hipMemsetAsync(gmax, 0, sizeof(unsigned int), stream);

  // fused: all f32->bf16 conversions + pos_raw basis (one dispatch)
  cvt_pos_fused<<<dim3(CVT_BLKS + POS_BLKS), 256, 0, stream>>>(
      x, Wq, Wk, Wv, We, Wrk, xb, Wqkvb, Web, Wrkb, pe_half, gmax);
  pos_assemble_kernel<<<(P2 * (FF / 2) + 255) / 256, 256, 0, stream>>>(pe_half, gmax, pe_b);

  // fused qkv (mode-6, reg+dbuf) + rk (mode-4, gload) in one grid
  bgemm_qkvrk<<<dim3(QKV_NWG + RK_NWG), 256, 0, stream>>>(
      xb, Wqkvb, rwb, rrb, Qwh, Qrh, Kh, Vt, pe_b, Wrkb, Rkh);

  // attention, decomposed: reg-staged S-gen + full-width PV GEMM
  attn_sgen<<<dim3(24 * 32 * 2), 256, 0, stream>>>(Qwh, Qrh, Kh, Rkh, Sp, s2);
  attn_pv<<<dim3(24 * 32), 128, 0, stream>>>(Sp, Vt, s2, ab_b);

  // final projection with bias (f32 out, 576 blocks, reg+dbuf path)
  bgemm_out<<<dim3((EE / 128) * ((BB * TT) / 128)), 256, 0, stream>>>(ab_b, Web, be, out);
}

// Round 25
// 315.461 us; speedup vs baseline: 1.0611x; 1.0611x over previous
//
#include <hip/hip_runtime.h>
#include <hip/hip_bf16.h>
#include <math.h>

// Problem constants
#define BB 4
#define TT 1536
#define CC 1536
#define HH 8
#define KK 64
#define VV 192
#define FF 192
#define EE 1536   // H*V
#define HK 512    // H*K
#define P2 3071   // 2T-1
#define RKROWS 3072  // P2 + 1 pad row (read by MFMA band, scatter-masked)
#define NQKV 2560    // HK + HK + EE (merged qkv weight rows)

typedef __attribute__((ext_vector_type(8))) __bf16 bf16x8;
typedef __attribute__((ext_vector_type(4))) float f32x4;
typedef __attribute__((ext_vector_type(4))) unsigned short us4;
typedef __attribute__((ext_vector_type(8))) unsigned short us8;

__device__ __forceinline__ unsigned short f2bf(float f) {
  union { float f; unsigned int u; } x; x.f = f;
  unsigned int r = x.u + 0x7fffu + ((x.u >> 16) & 1u);
  return (unsigned short)(r >> 16);
}

__device__ __forceinline__ void gload_lds16(const unsigned short* g, unsigned short* l) {
  __builtin_amdgcn_global_load_lds((const __attribute__((address_space(1))) unsigned int*)g,
                                   (__attribute__((address_space(3))) unsigned int*)l, 16, 0, 0);
}

// ---------------------------------------------------------------------------
// Fused f32 -> bf16 conversion for all six tensors (one dispatch).
// Segment sizes are compile-time; i indexes float4 groups.
// ---------------------------------------------------------------------------
#define N4_X  (BB * TT * CC / 4)   // 2359296
#define N4_W  (HK * CC / 4)        // 196608
#define N4_V  (EE * CC / 4)        // 589824
#define N4_E  (EE * EE / 4)        // 589824
#define N4_R  (HK * FF / 4)        // 24576
#define N4_TOT (N4_X + 2 * N4_W + N4_V + N4_E + N4_R)  // 3956736

__global__ void cvt_all(const float* __restrict__ x, const float* __restrict__ Wq,
                        const float* __restrict__ Wk, const float* __restrict__ Wv,
                        const float* __restrict__ We, const float* __restrict__ Wrk,
                        unsigned short* __restrict__ xb, unsigned short* __restrict__ Wqkvb,
                        unsigned short* __restrict__ Web, unsigned short* __restrict__ Wrkb) {
  int i = blockIdx.x * blockDim.x + threadIdx.x;
  if (i >= N4_TOT) return;
  const float* src;
  unsigned short* dst;
  int off;
  if (i < N4_X) {
    src = x; dst = xb; off = i;
  } else if (i < N4_X + N4_W) {
    src = Wq; dst = Wqkvb; off = i - N4_X;
  } else if (i < N4_X + 2 * N4_W) {
    src = Wk; dst = Wqkvb + (size_t)HK * CC; off = i - N4_X - N4_W;
  } else if (i < N4_X + 2 * N4_W + N4_V) {
    src = Wv; dst = Wqkvb + (size_t)2 * HK * CC; off = i - N4_X - 2 * N4_W;
  } else if (i < N4_X + 2 * N4_W + N4_V + N4_E) {
    src = We; dst = Web; off = i - N4_X - 2 * N4_W - N4_V;
  } else {
    src = Wrk; dst = Wrkb; off = i - N4_X - 2 * N4_W - N4_V - N4_E;
  }
  float4 v = *(const float4*)(src + (size_t)off * 4);
  us4 w;
  w[0] = f2bf(v.x); w[1] = f2bf(v.y); w[2] = f2bf(v.z); w[3] = f2bf(v.w);
  *(us4*)(dst + (size_t)off * 4) = w;
}

// ---------------------------------------------------------------------------
// Positional features, pass 1 (unchanged, validated)
// ---------------------------------------------------------------------------
__global__ void pos_raw_kernel(float* __restrict__ pe_half, unsigned int* __restrict__ gmax) {
  int m = blockIdx.x * blockDim.x + threadIdx.x;
  if (m >= P2) return;
  float p = (float)(m - (TT - 1));
  float ap = fabsf(p);
  const int fs = FF / 6;  // 32
  float* row = pe_half + (size_t)m * (FF / 2);

  const double lo = 3.0, hi = log2((double)TT);
  for (int i = 0; i < fs; ++i) {
    double hl = exp2(lo + (hi - lo) * (double)i / (double)(fs - 1));
    row[i] = exp2f((float)(-(double)ap / hl));
  }
  for (int i = 0; i < fs; ++i) {
    float w = exp2f((float)(i + 1)) - 1.0f;
    row[fs + i] = (w > ap) ? 1.0f : 0.0f;
  }
  float lmax = 0.0f;
  const float stddev = (float)TT / (2.0f * (float)fs);
  for (int i = 0; i < fs; ++i) {
    float mean = (float)((double)TT / fs + ((double)TT - (double)TT / fs) * (double)i / (double)(fs - 1));
    float conc = (mean / stddev) * (mean / stddev);
    float rate = mean / (stddev * stddev);
    float logp;
    if (ap > 0.0f)
      logp = (conc - 1.0f) * logf(ap) - rate * ap - (lgammaf(conc) - conc * logf(rate));
    else
      logp = -INFINITY;
    float prob = expf(logp) + 1e-8f;
    row[2 * fs + i] = prob;
    lmax = fmaxf(lmax, prob);
  }
  atomicMax(gmax, __float_as_uint(lmax));
}

// pass 2: normalize gamma, assemble full pe (bf16) with sign copy
__global__ void pos_assemble_kernel(const float* __restrict__ pe_half,
                                    const unsigned int* __restrict__ gmax,
                                    unsigned short* __restrict__ pe_b) {
  int idx = blockIdx.x * blockDim.x + threadIdx.x;
  if (idx >= P2 * (FF / 2)) return;
  int m = idx / (FF / 2);
  int f = idx % (FF / 2);
  float val = pe_half[idx];
  if (f >= 2 * (FF / 6)) val = val / __uint_as_float(*gmax);
  float p = (float)(m - (TT - 1));
  float sign = (p > 0.0f) ? 1.0f : ((p < 0.0f) ? -1.0f : 0.0f);
  pe_b[(size_t)m * FF + f] = f2bf(val);
  pe_b[(size_t)m * FF + (FF / 2) + f] = f2bf(sign * val);
}

// ---------------------------------------------------------------------------
// bf16 MFMA GEMM body (r22-validated logic, bid/nwg explicit so independent
// GEMMs can be co-dispatched in one grid). 128x128 tile, BK=32, 4 waves,
// XCD-chunked swizzle. RSTG=true: reg-staged + LDS dbuf, 1 barrier/K-step.
// RSTG=false: global_load_lds, 2 barriers/K-step.
// MODE 1: f32 out + bias. MODE 4: Rkh. MODE 6: merged qkv epilogue.
// ---------------------------------------------------------------------------
template <int MODE, bool RSTG>
__device__ __forceinline__ void bgemm_body(unsigned short* As, unsigned short* Bs,
                                           int bid, int nwg,
                                           const unsigned short* __restrict__ A,
                                           const unsigned short* __restrict__ Bw,
                                           const float* __restrict__ bias,
                                           const float* __restrict__ bias2,
                                           float* __restrict__ Cc,
                                           unsigned short* __restrict__ O1,
                                           unsigned short* __restrict__ O2,
                                           unsigned short* __restrict__ O3,
                                           unsigned short* __restrict__ O4,
                                           int M, int N, int Kd) {
  const int tid = threadIdx.x;
  const int lane = tid & 63;
  const int wave = tid >> 6;
  const int fr = lane & 15, fq = lane >> 4;
  const int wrow = (wave >> 1) * 64, wcol = (wave & 1) * 64;

  // XCD-chunked swizzle (bijective; nwg % 8 == 0)
  const int nbx = N >> 7;
  const int swz = (bid & 7) * (nwg >> 3) + (bid >> 3);
  const int row0 = (swz / nbx) * 128, col0 = (swz % nbx) * 128;

  const int r_c0 = tid >> 2, s_c0 = tid & 3;
  const int r_c1 = (tid + 256) >> 2, s_c1 = tid & 3;
  const int sw_c0 = s_c0 ^ ((r_c0 >> 1) & 3);
  const int sw_c1 = s_c1 ^ ((r_c1 >> 1) & 3);
  const unsigned short* Asrc0 = A + (size_t)(row0 + r_c0) * Kd + sw_c0 * 8;
  const unsigned short* Asrc1 = A + (size_t)(row0 + r_c1) * Kd + sw_c1 * 8;
  const unsigned short* Bsrc0 = Bw + (size_t)(col0 + r_c0) * Kd + sw_c0 * 8;
  const unsigned short* Bsrc1 = Bw + (size_t)(col0 + r_c1) * Kd + sw_c1 * 8;

  int aoff[4], boff[4];
#pragma unroll
  for (int m = 0; m < 4; ++m) {
    int rl = wrow + m * 16 + fr;
    aoff[m] = rl * 32 + (fq ^ ((rl >> 1) & 3)) * 8;
    int cl = wcol + m * 16 + fr;
    boff[m] = cl * 32 + (fq ^ ((cl >> 1) & 3)) * 8;
  }

  f32x4 acc[4][4];
#pragma unroll
  for (int m = 0; m < 4; ++m)
#pragma unroll
    for (int n = 0; n < 4; ++n) acc[m][n] = (f32x4){0.f, 0.f, 0.f, 0.f};

  if (RSTG) {
    // ---- reg-staged + LDS dbuf: one barrier per K-step ----
    us8 rA0 = *(const us8*)(Asrc0);
    us8 rA1 = *(const us8*)(Asrc1);
    us8 rB0 = *(const us8*)(Bsrc0);
    us8 rB1 = *(const us8*)(Bsrc1);
    *(us8*)(As + (size_t)tid * 8) = rA0;
    *(us8*)(As + (size_t)(tid + 256) * 8) = rA1;
    *(us8*)(Bs + (size_t)tid * 8) = rB0;
    *(us8*)(Bs + (size_t)(tid + 256) * 8) = rB1;
    __syncthreads();  // buf0 published

    int cur = 0;
    for (int kt = 0; kt < Kd; kt += 32) {
      const bool nx = (kt + 32 < Kd);
      if (nx) {
        rA0 = *(const us8*)(Asrc0 + kt + 32);
        rA1 = *(const us8*)(Asrc1 + kt + 32);
        rB0 = *(const us8*)(Bsrc0 + kt + 32);
        rB1 = *(const us8*)(Bsrc1 + kt + 32);
      }

      const unsigned short* Ab = As + cur * (128 * 32);
      const unsigned short* Bb = Bs + cur * (128 * 32);
      bf16x8 af[4], bfr[4];
#pragma unroll
      for (int m = 0; m < 4; ++m) af[m] = *(const bf16x8*)(Ab + aoff[m]);
#pragma unroll
      for (int n = 0; n < 4; ++n) bfr[n] = *(const bf16x8*)(Bb + boff[n]);
      __builtin_amdgcn_s_setprio(1);
#pragma unroll
      for (int m = 0; m < 4; ++m)
#pragma unroll
        for (int n = 0; n < 4; ++n)
          acc[m][n] = __builtin_amdgcn_mfma_f32_16x16x32_bf16(af[m], bfr[n], acc[m][n], 0, 0, 0);
      __builtin_amdgcn_s_setprio(0);

      if (nx) {
        const int nb = cur ^ 1;
        *(us8*)(As + nb * (128 * 32) + (size_t)tid * 8) = rA0;
        *(us8*)(As + nb * (128 * 32) + (size_t)(tid + 256) * 8) = rA1;
        *(us8*)(Bs + nb * (128 * 32) + (size_t)tid * 8) = rB0;
        *(us8*)(Bs + nb * (128 * 32) + (size_t)(tid + 256) * 8) = rB1;
      }
      __syncthreads();  // seals this iter's reads + publishes buf nb
      cur ^= 1;
    }
  } else {
    // ---- global_load_lds path ----
    unsigned short* Adst0 = As + (size_t)tid * 8;
    unsigned short* Adst1 = As + (size_t)(tid + 256) * 8;
    unsigned short* Bdst0 = Bs + (size_t)tid * 8;
    unsigned short* Bdst1 = Bs + (size_t)(tid + 256) * 8;
    for (int kt = 0; kt < Kd; kt += 32) {
      gload_lds16(Asrc0 + kt, Adst0);
      gload_lds16(Asrc1 + kt, Adst1);
      gload_lds16(Bsrc0 + kt, Bdst0);
      gload_lds16(Bsrc1 + kt, Bdst1);
      __syncthreads();

      bf16x8 af[4], bfr[4];
#pragma unroll
      for (int m = 0; m < 4; ++m) af[m] = *(const bf16x8*)(As + aoff[m]);
#pragma unroll
      for (int n = 0; n < 4; ++n) bfr[n] = *(const bf16x8*)(Bs + boff[n]);
#pragma unroll
      for (int m = 0; m < 4; ++m)
#pragma unroll
        for (int n = 0; n < 4; ++n)
          acc[m][n] = __builtin_amdgcn_mfma_f32_16x16x32_bf16(af[m], bfr[n], acc[m][n], 0, 0, 0);
      __syncthreads();
    }
  }

#pragma unroll
  for (int m = 0; m < 4; ++m) {
    int Rbase = row0 + wrow + m * 16 + fq * 4;
#pragma unroll
    for (int n = 0; n < 4; ++n) {
      int Cg = col0 + wcol + n * 16 + fr;
      if (MODE == 1) {
        float bv = bias[Cg];
#pragma unroll
        for (int r = 0; r < 4; ++r)
          Cc[(size_t)(Rbase + r) * N + Cg] = acc[m][n][r] + bv;
      } else if (MODE == 4) {
        int h = Cg >> 6, k0 = Cg & 63;
#pragma unroll
        for (int r = 0; r < 4; ++r)
          O1[(((size_t)h * RKROWS + (Rbase + r)) * KK + k0)] = f2bf(acc[m][n][r]);
      } else if (MODE == 6) {
        if (Cg < HK) {
          int h = Cg >> 6, k0 = Cg & 63;
          float bw = bias[Cg], br = bias2[Cg];
#pragma unroll
          for (int r = 0; r < 4; ++r) {
            int R = Rbase + r;
            int b = R / TT, t = R - b * TT;
            size_t di = ((((size_t)b * HH + h) * TT + t) * KK + k0);
            float qv = acc[m][n][r] * 0.125f;
            O1[di] = f2bf(qv + bw);
            O2[di] = f2bf(qv + br);
          }
        } else if (Cg < 2 * HK) {
          int c = Cg - HK;
          int h = c >> 6, k0 = c & 63;
#pragma unroll
          for (int r = 0; r < 4; ++r) {
            int R = Rbase + r;
            int b = R / TT, t = R - b * TT;
            O3[((((size_t)b * HH + h) * TT + t) * KK + k0)] = f2bf(acc[m][n][r]);
          }
        } else {
          int c = Cg - 2 * HK;
          int h = c / VV, v0 = c - h * VV;
#pragma unroll
          for (int r = 0; r < 4; ++r) {
            int R = Rbase + r;
            int b = R / TT, t = R - b * TT;
            O4[((((size_t)b * HH + h) * VV + v0) * TT + t)] = f2bf(acc[m][n][r]);
          }
        }
      }
    }
  }
}

// Fused qkv (960 blocks, mode-6 dbuf) + rk (96 blocks, mode-4 gload):
// rk's blocks fill CUs during qkv's ramp/tail instead of a standalone
// under-occupied dispatch. Branch is block-uniform -> barriers safe.
#define QKV_NWG ((NQKV / 128) * ((BB * TT) / 128))   // 960
#define RK_NWG  ((HK / 128) * (RKROWS / 128))        // 96

__global__ __launch_bounds__(256) void bgemm_qkvrk(const unsigned short* __restrict__ xb,
                                                   const unsigned short* __restrict__ Wqkvb,
                                                   const float* __restrict__ rwb,
                                                   const float* __restrict__ rrb,
                                                   unsigned short* __restrict__ Qwh,
                                                   unsigned short* __restrict__ Qrh,
                                                   unsigned short* __restrict__ Kh,
                                                   unsigned short* __restrict__ Vt,
                                                   const unsigned short* __restrict__ pe_b,
                                                   const unsigned short* __restrict__ Wrkb,
                                                   unsigned short* __restrict__ Rkh) {
  __shared__ __align__(16) unsigned short As[2 * 128 * 32];
  __shared__ __align__(16) unsigned short Bs[2 * 128 * 32];
  if ((int)blockIdx.x < QKV_NWG) {
    bgemm_body<6, true>(As, Bs, blockIdx.x, QKV_NWG, xb, Wqkvb, rwb, rrb,
                        nullptr, Qwh, Qrh, Kh, Vt, BB * TT, NQKV, CC);
  } else {
    bgemm_body<4, false>(As, Bs, blockIdx.x - QKV_NWG, RK_NWG, pe_b, Wrkb, nullptr, nullptr,
                         nullptr, Rkh, nullptr, nullptr, nullptr, RKROWS, HK, FF);
  }
}

// Standalone final projection (mode-1, gload path)
__global__ __launch_bounds__(256) void bgemm_out(const unsigned short* __restrict__ ab_b,
                                                 const unsigned short* __restrict__ Web,
                                                 const float* __restrict__ be,
                                                 float* __restrict__ out) {
  __shared__ __align__(16) unsigned short As[128 * 32];
  __shared__ __align__(16) unsigned short Bs[128 * 32];
  bgemm_body<1, false>(As, Bs, blockIdx.x, gridDim.x, ab_b, Web, be, nullptr,
                       out, nullptr, nullptr, nullptr, nullptr, BB * TT, EE, EE);
}

// ---------------------------------------------------------------------------
// Kernel A: S-GEN with REG-STAGED K/R (r18-validated). Padded LDS rows (72
// shorts). Grid: 1536 = (q-block, panel, kv-half), XCD-chunk-swizzled.
// ---------------------------------------------------------------------------
__global__ __launch_bounds__(256) void attn_sgen(const unsigned short* __restrict__ Qwh,
                                                 const unsigned short* __restrict__ Qrh,
                                                 const unsigned short* __restrict__ Kh,
                                                 const unsigned short* __restrict__ Rkh,
                                                 unsigned short* __restrict__ S,
                                                 float* __restrict__ s2) {
  const int bid = blockIdx.x;
  const int Lid = (bid & 7) * 192 + (bid >> 3);
  const int kvh = Lid & 1;
  const int q0 = ((Lid >> 1) % 24) * 64;
  const int panel = Lid / 48;               // = b*8 + h
  const int h = panel & 7;

  const int tid = threadIdx.x;
  const int wave = tid >> 6, lane = tid & 63;
  const int fr = lane & 15, fq = lane >> 4;
  const int kof = fq * 8;
  const int qs = q0 + wave * 16;
  const int qlb = fq * 4;

  __shared__ __align__(16) unsigned short Ks[64 * 72];    //  9216 B (+8 pad rows)
  __shared__ __align__(16) unsigned short Rs[128 * 72];   // 18432 B
  __shared__ __align__(16) float Lsm[4][16][68];          // 17408 B
  float(*Lw)[68] = Lsm[wave];

  const unsigned short* Qwp = Qwh + (size_t)panel * TT * KK;
  const unsigned short* Qrp = Qrh + (size_t)panel * TT * KK;
  const unsigned short* Kp  = Kh  + (size_t)panel * TT * KK;
  const unsigned short* Rp  = Rkh + (size_t)h * RKROWS * KK;
  unsigned short* Sp = S + (size_t)panel * TT * TT;

  // staging geometry: chunk row = tid>>3 (+32 per extra chunk), slot = (tid&7)*8
  const int crow = tid >> 3;        // 0..31
  const int csl  = (tid & 7) * 8;   // short offset within row

  bf16x8 aw[2], arr[2];
  {
    const unsigned short* qw = Qwp + (size_t)(qs + fr) * KK;
    const unsigned short* qr = Qrp + (size_t)(qs + fr) * KK;
    aw[0]  = *(const bf16x8*)(qw + kof);
    aw[1]  = *(const bf16x8*)(qw + 32 + kof);
    arr[0] = *(const bf16x8*)(qr + kof);
    arr[1] = *(const bf16x8*)(qr + 32 + kof);
  }

  float s_run[4] = {0.f, 0.f, 0.f, 0.f};
  const int srow = lane >> 2;        // repack: lane's source row
  const int scg = (lane & 3) * 16;   // repack: lane's col group

  // prologue: load tile 0 into regs, write to LDS (visible after 1st barrier)
  {
    const int j0 = kvh * 64;
    const unsigned short* kb = Kp + (size_t)(j0 + crow) * KK + csl;
    us8 k0 = *(const us8*)(kb);
    us8 k1 = *(const us8*)(kb + 32 * KK);
    const unsigned short* rb = Rp + (size_t)(1472 + j0 - q0 + crow) * KK + csl;
    us8 r0 = *(const us8*)(rb);
    us8 r1 = *(const us8*)(rb + 32 * KK);
    us8 r2 = *(const us8*)(rb + 64 * KK);
    us8 r3 = *(const us8*)(rb + 96 * KK);
    unsigned short* kd = Ks + (size_t)crow * 72 + csl;
    *(us8*)(kd) = k0;
    *(us8*)(kd + 32 * 72) = k1;
    unsigned short* rd = Rs + (size_t)crow * 72 + csl;
    *(us8*)(rd) = r0;
    *(us8*)(rd + 32 * 72) = r1;
    *(us8*)(rd + 64 * 72) = r2;
    *(us8*)(rd + 96 * 72) = r3;
  }

  for (int t = 0; t < 12; ++t) {
    const int j0 = kvh * 64 + t * 128;
    __syncthreads();  // tile t's ds_writes visible to all waves

    // ---- issue next tile's global loads EARLY (drain under compute) ----
    us8 nK0, nK1, nR0, nR1, nR2, nR3;
    if (t + 1 < 12) {
      const int jn = j0 + 128;
      const unsigned short* kb = Kp + (size_t)(jn + crow) * KK + csl;
      nK0 = *(const us8*)(kb);
      nK1 = *(const us8*)(kb + 32 * KK);
      const unsigned short* rb = Rp + (size_t)(1472 + jn - q0 + crow) * KK + csl;
      nR0 = *(const us8*)(rb);
      nR1 = *(const us8*)(rb + 32 * KK);
      nR2 = *(const us8*)(rb + 64 * KK);
      nR3 = *(const us8*)(rb + 96 * KK);
    }

    // ---- band logits from Rs: rows (48-16*wave) + tjb*16 + fr ----
    __builtin_amdgcn_s_setprio(1);
    f32x4 gfr[5];
#pragma unroll
    for (int tjb = 0; tjb < 5; ++tjb) {
      f32x4 acc = (f32x4){0.f, 0.f, 0.f, 0.f};
      bf16x8 bv0 = *(const bf16x8*)(Rs + (size_t)(48 - 16 * wave + tjb * 16 + fr) * 72 + kof);
      acc = __builtin_amdgcn_mfma_f32_16x16x32_bf16(arr[0], bv0, acc, 0, 0, 0);
      bf16x8 bv1 = *(const bf16x8*)(Rs + (size_t)(48 - 16 * wave + tjb * 16 + fr) * 72 + 32 + kof);
      acc = __builtin_amdgcn_mfma_f32_16x16x32_bf16(arr[1], bv1, acc, 0, 0, 0);
      gfr[tjb] = acc;
    }
    __builtin_amdgcn_s_setprio(0);
    // scatter-shift: L[q][j], j = band + q - 15 (masked; covers [0,64) fully)
#pragma unroll
    for (int tjb = 0; tjb < 5; ++tjb)
#pragma unroll
      for (int rr = 0; rr < 4; ++rr) {
        int j = tjb * 16 + fr + qlb + rr - 15;
        if (j >= 0 && j < 64) Lw[qlb + rr][j] = gfr[tjb][rr];
      }

    // ---- content logits from Ks ----
    __builtin_amdgcn_s_setprio(1);
    f32x4 cfr[4];
#pragma unroll
    for (int tj = 0; tj < 4; ++tj) {
      f32x4 acc = (f32x4){0.f, 0.f, 0.f, 0.f};
      bf16x8 bv0 = *(const bf16x8*)(Ks + (size_t)(tj * 16 + fr) * 72 + kof);
      acc = __builtin_amdgcn_mfma_f32_16x16x32_bf16(aw[0], bv0, acc, 0, 0, 0);
      bf16x8 bv1 = *(const bf16x8*)(Ks + (size_t)(tj * 16 + fr) * 72 + 32 + kof);
      acc = __builtin_amdgcn_mfma_f32_16x16x32_bf16(aw[1], bv1, acc, 0, 0, 0);
      cfr[tj] = acc;
    }
    __builtin_amdgcn_s_setprio(0);

    // ---- streaming exp: p = exp(content + rel - 20) -> Lw; s += p ----
#pragma unroll
    for (int tj = 0; tj < 4; ++tj)
#pragma unroll
      for (int rr = 0; rr < 4; ++rr) {
        float p = __expf(cfr[tj][rr] + Lw[qlb + rr][tj * 16 + fr] - 20.0f);
        Lw[qlb + rr][tj * 16 + fr] = p;
        s_run[rr] += p;
      }

    // ---- repack + coalesced bf16 store (wave-local LDS roundtrip) ----
    {
      f32x4 v0 = *(const f32x4*)&Lw[srow][scg + 0];
      f32x4 v1 = *(const f32x4*)&Lw[srow][scg + 4];
      f32x4 v2 = *(const f32x4*)&Lw[srow][scg + 8];
      f32x4 v3 = *(const f32x4*)&Lw[srow][scg + 12];
      us8 w0, w1;
#pragma unroll
      for (int i = 0; i < 4; ++i) {
        w0[i] = f2bf(v0[i]); w0[4 + i] = f2bf(v1[i]);
        w1[i] = f2bf(v2[i]); w1[4 + i] = f2bf(v3[i]);
      }
      unsigned short* dst = Sp + (size_t)(qs + srow) * TT + j0 + scg;
      *(us8*)(dst) = w0;
      *(us8*)(dst + 8) = w1;
    }

    __syncthreads();  // all waves done reading Ks/Rs for tile t

    // ---- write next tile's staged regs to LDS ----
    if (t + 1 < 12) {
      unsigned short* kd = Ks + (size_t)crow * 72 + csl;
      *(us8*)(kd) = nK0;
      *(us8*)(kd + 32 * 72) = nK1;
      unsigned short* rd = Rs + (size_t)crow * 72 + csl;
      *(us8*)(rd) = nR0;
      *(us8*)(rd + 32 * 72) = nR1;
      *(us8*)(rd + 64 * 72) = nR2;
      *(us8*)(rd + 96 * 72) = nR3;
    }
  }

  // ---- s partials: reduce over 16 fr lanes, write per-half slot ----
#pragma unroll
  for (int rr = 0; rr < 4; ++rr) {
    float s = s_run[rr];
    s += __shfl_xor(s, 1);
    s += __shfl_xor(s, 2);
    s += __shfl_xor(s, 4);
    s += __shfl_xor(s, 8);
    if (fr == 0)
      s2[((size_t)kvh * 32 + panel) * TT + qs + qlb + rr] = s;
  }
}

// ---------------------------------------------------------------------------
// Kernel B: PV GEMM, full-width 64x192 tile (r16, validated). S read once;
// Vt panel served from L2 (panel's 24 row-blocks on one XCD via swizzle).
// ---------------------------------------------------------------------------
__global__ __launch_bounds__(128) void attn_pv(const unsigned short* __restrict__ S,
                                               const unsigned short* __restrict__ Vt,
                                               const float* __restrict__ s2,
                                               unsigned short* __restrict__ ab) {
  __shared__ __align__(16) unsigned short As[64 * 32];    // 4 KB
  __shared__ __align__(16) unsigned short Bs[192 * 32];   // 12 KB
  const int bid = blockIdx.x;
  const int Lid = (bid & 7) * 96 + (bid >> 3);   // XCD-chunk swizzle
  const int rowblk = Lid % 24;
  const int panel = Lid / 24;              // = b*8 + h
  const int b = panel >> 3, h = panel & 7;
  const int row0 = rowblk * 64;

  const int tid = threadIdx.x;
  const int lane = tid & 63;
  const int wave = tid >> 6;  // 0..1
  const int fr = lane & 15, fq = lane >> 4;

  const unsigned short* Ap = S + (size_t)panel * TT * TT + (size_t)row0 * TT;
  const unsigned short* Bp = Vt + (size_t)panel * VV * TT;

  int offA[2]; unsigned short* dA[2];
#pragma unroll
  for (int c = 0; c < 2; ++c) {
    int cid = tid + 128 * c, r = cid >> 2, s = cid & 3;
    offA[c] = r * TT + ((s ^ ((r >> 1) & 3)) * 8);
    dA[c] = As + (size_t)cid * 8;
  }
  int offB[6]; unsigned short* dB[6];
#pragma unroll
  for (int c = 0; c < 6; ++c) {
    int cid = tid + 128 * c, r = cid >> 2, s = cid & 3;
    offB[c] = r * TT + ((s ^ ((r >> 1) & 3)) * 8);
    dB[c] = Bs + (size_t)cid * 8;
  }

  int aoff[4], boff[6];
#pragma unroll
  for (int m = 0; m < 4; ++m) {
    int rl = m * 16 + fr;
    aoff[m] = rl * 32 + (fq ^ ((rl >> 1) & 3)) * 8;
  }
#pragma unroll
  for (int n = 0; n < 6; ++n) {
    int cl = wave * 96 + n * 16 + fr;
    boff[n] = cl * 32 + (fq ^ ((cl >> 1) & 3)) * 8;
  }

  f32x4 acc[4][6];
#pragma unroll
  for (int m = 0; m < 4; ++m)
#pragma unroll
    for (int n = 0; n < 6; ++n) acc[m][n] = (f32x4){0.f, 0.f, 0.f, 0.f};

  for (int kt = 0; kt < TT; kt += 32) {
#pragma unroll
    for (int c = 0; c < 2; ++c) gload_lds16(Ap + offA[c] + kt, dA[c]);
#pragma unroll
    for (int c = 0; c < 6; ++c) gload_lds16(Bp + offB[c] + kt, dB[c]);
    __syncthreads();

    bf16x8 af[4], bfv[6];
#pragma unroll
    for (int m = 0; m < 4; ++m) af[m] = *(const bf16x8*)(As + aoff[m]);
#pragma unroll
    for (int n = 0; n < 6; ++n) bfv[n] = *(const bf16x8*)(Bs + boff[n]);
    __builtin_amdgcn_s_setprio(1);
#pragma unroll
    for (int m = 0; m < 4; ++m)
#pragma unroll
      for (int n = 0; n < 6; ++n)
        acc[m][n] = __builtin_amdgcn_mfma_f32_16x16x32_bf16(af[m], bfv[n], acc[m][n], 0, 0, 0);
    __builtin_amdgcn_s_setprio(0);
    __syncthreads();
  }

  const float* sA = s2 + (size_t)panel * TT;
  const float* sB = s2 + (size_t)(32 + panel) * TT;
#pragma unroll
  for (int m = 0; m < 4; ++m) {
    int Rbase = row0 + m * 16 + fq * 4;
    float invr[4];
#pragma unroll
    for (int r = 0; r < 4; ++r) invr[r] = 1.0f / (sA[Rbase + r] + sB[Rbase + r]);
#pragma unroll
    for (int n = 0; n < 6; ++n) {
      int v = wave * 96 + n * 16 + fr;
#pragma unroll
      for (int r = 0; r < 4; ++r)
        ab[((size_t)(b * TT + Rbase + r)) * EE + h * VV + v] = f2bf(acc[m][n][r] * invr[r]);
    }
  }
}

// ---------------------------------------------------------------------------
extern "C" void kernel_launch(void* const* d_in, const int* in_sizes, int n_in,
                              void* d_out, int out_size, void* d_ws, size_t ws_size,
                              hipStream_t stream) {
  const float* x   = (const float*)d_in[0];
  const float* Wq  = (const float*)d_in[1];
  const float* Wk  = (const float*)d_in[2];
  const float* Wv  = (const float*)d_in[3];
  const float* Wrk = (const float*)d_in[4];
  const float* rwb = (const float*)d_in[5];
  const float* rrb = (const float*)d_in[6];
  const float* We  = (const float*)d_in[7];
  const float* be  = (const float*)d_in[8];
  float* out = (float*)d_out;

  size_t off = 0;
  auto alloc = [&](size_t bytes) -> void* {
    void* p = (char*)d_ws + off;
    off += (bytes + 255) & ~(size_t)255;
    return p;
  };
  unsigned int* gmax = (unsigned int*)alloc(sizeof(unsigned int));
  float* pe_half = (float*)alloc((size_t)P2 * (FF / 2) * 4);
  unsigned short* pe_b   = (unsigned short*)alloc((size_t)RKROWS * FF * 2);  // row 3071 = pad
  unsigned short* xb     = (unsigned short*)alloc((size_t)BB * TT * CC * 2);
  unsigned short* Wqkvb  = (unsigned short*)alloc((size_t)NQKV * CC * 2);
  unsigned short* Web    = (unsigned short*)alloc((size_t)EE * EE * 2);
  unsigned short* Wrkb   = (unsigned short*)alloc((size_t)HK * FF * 2);
  unsigned short* Qwh    = (unsigned short*)alloc((size_t)BB * HH * TT * KK * 2);
  unsigned short* Qrh    = (unsigned short*)alloc((size_t)BB * HH * TT * KK * 2);
  unsigned short* Kh     = (unsigned short*)alloc((size_t)BB * HH * TT * KK * 2);
  unsigned short* Rkh    = (unsigned short*)alloc((size_t)HH * RKROWS * KK * 2);
  unsigned short* Vt     = (unsigned short*)alloc((size_t)BB * HH * VV * TT * 2);
  unsigned short* ab_b   = (unsigned short*)alloc((size_t)BB * TT * EE * 2);
  unsigned short* Sp     = (unsigned short*)alloc((size_t)BB * HH * TT * TT * 2);  // 151 MB
  float* s2              = (float*)alloc((size_t)2 * 32 * TT * 4);

  hipMemsetAsync(gmax, 0, sizeof(unsigned int), stream);

  pos_raw_kernel<<<(P2 + 255) / 256, 256, 0, stream>>>(pe_half, gmax);
  pos_assemble_kernel<<<(P2 * (FF / 2) + 255) / 256, 256, 0, stream>>>(pe_half, gmax, pe_b);

  // all six f32->bf16 conversions in one dispatch
  cvt_all<<<(N4_TOT + 255) / 256, 256, 0, stream>>>(
      x, Wq, Wk, Wv, We, Wrk, xb, Wqkvb, Web, Wrkb);

  // fused qkv (mode-6, reg+dbuf) + rk (mode-4, gload) in one grid
  bgemm_qkvrk<<<dim3(QKV_NWG + RK_NWG), 256, 0, stream>>>(
      xb, Wqkvb, rwb, rrb, Qwh, Qrh, Kh, Vt, pe_b, Wrkb, Rkh);

  // attention, decomposed: reg-staged S-gen + full-width PV GEMM
  attn_sgen<<<dim3(24 * 32 * 2), 256, 0, stream>>>(Qwh, Qrh, Kh, Rkh, Sp, s2);
  attn_pv<<<dim3(24 * 32), 128, 0, stream>>>(Sp, Vt, s2, ab_b);

  // final projection with bias (f32 out, 576 blocks)
  bgemm_out<<<dim3((EE / 128) * ((BB * TT) / 128)), 256, 0, stream>>>(ab_b, Web, be, out);
}